// Round 2
// baseline (164.963 us; speedup 1.0000x reference)
//
#include <hip/hip_runtime.h>

#define NMS_NUM_CLASSES 16
#define NMS_N 2048
#define NMS_IOU_TH 0.5f
#define NMS_SCORE_TH 0.05f
#define NMS_MAX_DET 100
#define NMS_MAX_PER_CLASS 100
#define NMS_NS (NMS_NUM_CLASSES * NMS_MAX_PER_CLASS)   // 1600
#define NMS_TILE 128

// SESSION PITFALLS (r1-r21):
//  * float4 casts on __shared__ float -> ds_read_b128 misalignment fault.
//  * u64 LDS arrays / LDS pointer casts correlated with container deaths.
//    ONLY declared __shared__ float/uint/uchar arrays, scalar access.
//  * Serial NMS chains cost 45-65 us at M~122 -> Jacobi fixpoint (r15).
//  * Fusion via grid.sync REGRESSED (+5us): launch gaps ~1.4us in graphs.
//  * r19: k1 = F~2us issue + W~37us stall. r20 removed ~6 of ~14 barriers:
//    NO change (113.6 vs 111.8). Barrier count is NOT the cost. Counters:
//    VALUBusy 2.9%, occupancy 4.2% -> 16-wave block crawls latency-bound
//    through micro-phases where most waves have <1 task.
//  * r21 (this round): SINGLE-WAVE blocks (64 thr). Lane l owns candidates
//    l and l+64 (M~122 fits one tile). Wave-synchronous everything:
//      - compact: per-lane bitmask + shfl prefix scan, no LDS atomics
//      - rank: lane-owned accumulators, broadcast s_scu[j] reads
//      - suppression masks in 8 VGPRs/lane, Jacobi keep-words via __ballot
//        (whole fixpoint register-resident, ~25 inst/round)
//      - zero barriers on critical path (3 residual s_barrier = immediate
//        for a 1-wave group)
//    General M>128 stays correct: tile loop + A0 pass + slow rank path.

// ---------------------------------------------------------------------------
// Kernel 1: one block per (image, class), 64 threads (ONE wave).
// ---------------------------------------------------------------------------
__global__ __launch_bounds__(64) void nms_per_class_kernel(
    const float* __restrict__ pred,   // [B, N, 6] x1,y1,x2,y2,cls,score
    float* __restrict__ ws_scores,    // [B, 1600]
    float* __restrict__ ws_boxes,     // [B, 1600, 4]
    float* __restrict__ out,          // [B*600] rows + [B] nvalid
    int B)
{
    const int b = blockIdx.x / NMS_NUM_CLASSES;
    const int c = blockIdx.x % NMS_NUM_CLASSES;
    const float* p = pred + (size_t)b * NMS_N * 6;
    const int lane = threadIdx.x;            // 0..63, one wave

    // zero-init output for this image (k2 is a later dispatch on the stream)
    if (c == 0) {
        float* ob = out + (size_t)b * NMS_MAX_DET * 6;
        for (int t = lane; t < NMS_MAX_DET * 6; t += 64) ob[t] = 0.0f;
        if (lane == 0) out[(size_t)B * NMS_MAX_DET * 6 + b] = 0.0f;
    }

    __shared__ float s_scu[NMS_N];           // unsorted scores
    __shared__ int   s_ixu[NMS_N];           // unsorted original indices
    __shared__ float s_bxu[NMS_N * 4];       // unsorted boxes
    __shared__ float s_sc[NMS_N];            // sorted scores
    __shared__ float s_bx[NMS_N * 4];        // sorted boxes
    __shared__ unsigned char s_keep[NMS_N];

    // ---- Phase A: candidate scan; lane owns rows it*64+lane, bit it ----
    unsigned int okm = 0u;
    const float2* p2 = (const float2*)p;     // row i = p2[3i], p2[3i+1], p2[3i+2]
    #pragma unroll
    for (int it = 0; it < NMS_N / 64; ++it) {
        const int row = it * 64 + lane;
        float2 v2 = p2[row * 3 + 2];         // cls, score
        const bool ok = ((int)v2.x == c) && (v2.y > NMS_SCORE_TH);
        if (ok) okm |= (1u << it);
    }
    // exclusive prefix of per-lane counts (wave scan, no LDS)
    const int cnt = __popc(okm);
    int inc = cnt;
    for (int off = 1; off < 64; off <<= 1) {
        int n = __shfl_up(inc, off, 64);
        if (lane >= off) inc += n;
    }
    int pos = inc - cnt;                     // this lane's first slot
    const int M = __shfl(inc, 63, 64);       // total candidates (uniform)

    // ---- Phase B: gather candidate rows into LDS (L1-warm reloads) ----
    unsigned int rem = okm;
    while (rem) {
        const int it = __ffs(rem) - 1;
        rem &= rem - 1u;
        const int row = it * 64 + lane;
        float2 v0 = p2[row * 3 + 0];         // x1, y1
        float2 v1 = p2[row * 3 + 1];         // x2, y2
        float2 v2 = p2[row * 3 + 2];         // cls, score
        s_scu[pos] = v2.y;
        s_ixu[pos] = row;
        s_bxu[pos * 4 + 0] = v0.x;
        s_bxu[pos * 4 + 1] = v0.y;
        s_bxu[pos * 4 + 2] = v1.x;
        s_bxu[pos * 4 + 3] = v1.y;
        ++pos;
    }
    __syncthreads();                         // 1-wave group: immediate

    // ---- rank sort + scatter (comparator identical to r12-proven) ----
    if (M <= 2 * 64) {
        // fast path: lane owns slots lane and lane+64
        const int s0 = lane, s1 = lane + 64;
        const bool h0 = s0 < M, h1 = s1 < M;
        float sc0 = 0.0f, sc1 = 0.0f;
        int   ix0 = 0,    ix1 = 0;
        float b00 = 0, b01 = 0, b02 = 0, b03 = 0;
        float b10 = 0, b11 = 0, b12 = 0, b13 = 0;
        if (h0) {
            sc0 = s_scu[s0]; ix0 = s_ixu[s0];
            b00 = s_bxu[s0 * 4 + 0]; b01 = s_bxu[s0 * 4 + 1];
            b02 = s_bxu[s0 * 4 + 2]; b03 = s_bxu[s0 * 4 + 3];
        }
        if (h1) {
            sc1 = s_scu[s1]; ix1 = s_ixu[s1];
            b10 = s_bxu[s1 * 4 + 0]; b11 = s_bxu[s1 * 4 + 1];
            b12 = s_bxu[s1 * 4 + 2]; b13 = s_bxu[s1 * 4 + 3];
        }
        int rk0 = 0, rk1 = 0;
        for (int j = 0; j < M; ++j) {
            const float sj = s_scu[j];       // broadcast read
            const int   ij = s_ixu[j];       // broadcast read
            rk0 += (sj > sc0) || (sj == sc0 && ij < ix0);
            rk1 += (sj > sc1) || (sj == sc1 && ij < ix1);
        }
        if (h0) {
            s_sc[rk0] = sc0;
            s_bx[rk0 * 4 + 0] = b00; s_bx[rk0 * 4 + 1] = b01;
            s_bx[rk0 * 4 + 2] = b02; s_bx[rk0 * 4 + 3] = b03;
            s_keep[rk0] = 1;
        }
        if (h1) {
            s_sc[rk1] = sc1;
            s_bx[rk1 * 4 + 0] = b10; s_bx[rk1 * 4 + 1] = b11;
            s_bx[rk1 * 4 + 2] = b12; s_bx[rk1 * 4 + 3] = b13;
            s_keep[rk1] = 1;
        }
    } else {
        // general path (M > 128): correct, not fast (bench data never here)
        for (int s = lane; s < M; s += 64) {
            const float sc = s_scu[s];
            const int   ix = s_ixu[s];
            int rk = 0;
            for (int j = 0; j < M; ++j) {
                const float sj = s_scu[j];
                const int   ij = s_ixu[j];
                rk += (sj > sc) || (sj == sc && ij < ix);
            }
            s_sc[rk] = sc;
            s_bx[rk * 4 + 0] = s_bxu[s * 4 + 0];
            s_bx[rk * 4 + 1] = s_bxu[s * 4 + 1];
            s_bx[rk * 4 + 2] = s_bxu[s * 4 + 2];
            s_bx[rk * 4 + 3] = s_bxu[s * 4 + 3];
            s_keep[rk] = 1;
        }
    }
    __syncthreads();                         // immediate (1 wave)

    // ---- tiled NMS: register-resident masks + ballot Jacobi ----
    for (int t0 = 0; t0 < M; t0 += NMS_TILE) {
        const int tm = (M - t0 < NMS_TILE) ? (M - t0) : NMS_TILE;

        // A0: suppression by kept candidates of earlier tiles (final state)
        if (t0 > 0) {
            for (int jj = lane; jj < tm; jj += 64) {
                const int gj = t0 + jj;
                float jx1 = s_bx[gj * 4 + 0], jy1 = s_bx[gj * 4 + 1];
                float jx2 = s_bx[gj * 4 + 2], jy2 = s_bx[gj * 4 + 3];
                float aj = (jy2 - jy1) * (jx2 - jx1);
                int dead = 0;
                for (int i = 0; i < t0 && !dead; ++i) {
                    if (!s_keep[i]) continue;
                    float ix1 = s_bx[i * 4 + 0], iy1 = s_bx[i * 4 + 1];
                    float ix2 = s_bx[i * 4 + 2], iy2 = s_bx[i * 4 + 3];
                    float ai = (iy2 - iy1) * (ix2 - ix1);
                    float ih = fminf(iy2, jy2) - fmaxf(iy1, jy1);
                    ih = fmaxf(ih, 0.0f);
                    float iw = fminf(ix2, jx2) - fmaxf(ix1, jx1);
                    iw = fmaxf(iw, 0.0f);
                    float inter = ih * iw;
                    float uni = ai + aj - inter;
                    float iou = (inter > 0.0f) ? inter / fmaxf(uni, 1e-08f) : 0.0f;
                    dead = iou > NMS_IOU_TH;
                }
                if (dead) s_keep[gj] = 0;
            }
            __syncthreads();                 // immediate (1 wave)
        }

        // lane owns tile columns j0=lane, j1=lane+64
        const int j0 = lane, j1 = lane + 64;
        const bool h0 = j0 < tm, h1 = j1 < tm;
        float a0x1 = 0, a0y1 = 0, a0x2 = 0, a0y2 = 0, ar0 = 0;
        float a1x1 = 0, a1y1 = 0, a1x2 = 0, a1y2 = 0, ar1 = 0;
        if (h0) {
            const int g = t0 + j0;
            a0x1 = s_bx[g * 4 + 0]; a0y1 = s_bx[g * 4 + 1];
            a0x2 = s_bx[g * 4 + 2]; a0y2 = s_bx[g * 4 + 3];
            ar0 = (a0y2 - a0y1) * (a0x2 - a0x1);
        }
        if (h1) {
            const int g = t0 + j1;
            a1x1 = s_bx[g * 4 + 0]; a1y1 = s_bx[g * 4 + 1];
            a1x2 = s_bx[g * 4 + 2]; a1y2 = s_bx[g * 4 + 3];
            ar1 = (a1y2 - a1y1) * (a1x2 - a1x1);
        }
        const int ext0 = h0 ? (int)s_keep[t0 + j0] : 0;
        const int ext1 = h1 ? (int)s_keep[t0 + j1] : 0;

        // suppressor masks in registers: m0w = suppressors of j0 (word w)
        unsigned int m00 = 0, m01 = 0, m02 = 0, m03 = 0;
        unsigned int m10 = 0, m11 = 0, m12 = 0, m13 = 0;
#define NMS_SUPW(W, MW0, MW1)                                                  \
        {                                                                      \
            const int i0 = (W) * 32;                                           \
            int ie = tm - i0; if (ie > 32) ie = 32;                            \
            for (int bb = 0; bb < ie; ++bb) {                                  \
                const int ii = i0 + bb;                                        \
                const int gi = t0 + ii;                                        \
                float ix1 = s_bx[gi * 4 + 0], iy1 = s_bx[gi * 4 + 1];          \
                float ix2 = s_bx[gi * 4 + 2], iy2 = s_bx[gi * 4 + 3];          \
                float ai = (iy2 - iy1) * (ix2 - ix1);                          \
                if (h0 && ii < j0) {                                           \
                    float ih = fminf(iy2, a0y2) - fmaxf(iy1, a0y1);            \
                    ih = fmaxf(ih, 0.0f);                                      \
                    float iw = fminf(ix2, a0x2) - fmaxf(ix1, a0x1);            \
                    iw = fmaxf(iw, 0.0f);                                      \
                    float inter = ih * iw;                                     \
                    float uni = ai + ar0 - inter;                              \
                    float iou = (inter > 0.0f) ? inter / fmaxf(uni, 1e-08f) : 0.0f; \
                    if (iou > NMS_IOU_TH) MW0 |= (1u << bb);                   \
                }                                                              \
                if (h1 && ii < j1) {                                           \
                    float ih = fminf(iy2, a1y2) - fmaxf(iy1, a1y1);            \
                    ih = fmaxf(ih, 0.0f);                                      \
                    float iw = fminf(ix2, a1x2) - fmaxf(ix1, a1x1);            \
                    iw = fmaxf(iw, 0.0f);                                      \
                    float inter = ih * iw;                                     \
                    float uni = ai + ar1 - inter;                              \
                    float iou = (inter > 0.0f) ? inter / fmaxf(uni, 1e-08f) : 0.0f; \
                    if (iou > NMS_IOU_TH) MW1 |= (1u << bb);                   \
                }                                                              \
            }                                                                  \
        }
        NMS_SUPW(0, m00, m10)
        NMS_SUPW(1, m01, m11)
        NMS_SUPW(2, m02, m12)
        NMS_SUPW(3, m03, m13)
#undef NMS_SUPW

        // Jacobi fixpoint, fully register/ballot-resident. Same recurrence
        // as r15/r20: newalive_r = ext && no living suppressor under alive_r.
        int alive0 = ext0, alive1 = ext1;
        for (int round = 0; round < NMS_TILE; ++round) {
            unsigned long long A0b = __ballot(alive0 != 0);  // cols 0..63
            unsigned long long A1b = __ballot(alive1 != 0);  // cols 64..127
            const unsigned int kw0 = (unsigned int)(A0b & 0xffffffffu);
            const unsigned int kw1 = (unsigned int)(A0b >> 32);
            const unsigned int kw2 = (unsigned int)(A1b & 0xffffffffu);
            const unsigned int kw3 = (unsigned int)(A1b >> 32);
            int na0 = 0, na1 = 0;
            if (ext0)
                na0 = (((m00 & kw0) | (m01 & kw1) | (m02 & kw2) | (m03 & kw3)) == 0u);
            if (ext1)
                na1 = (((m10 & kw0) | (m11 & kw1) | (m12 & kw2) | (m13 & kw3)) == 0u);
            const unsigned long long chg =
                __ballot(na0 != alive0) | __ballot(na1 != alive1);
            alive0 = na0; alive1 = na1;
            if (chg == 0ull) break;          // uniform
        }

        if (h0) s_keep[t0 + j0] = (unsigned char)alive0;
        if (h1) s_keep[t0 + j1] = (unsigned char)alive1;
        __syncthreads();                     // immediate (1 wave)
    }

    // ---- emit top-100 kept in sorted order (r20-proven wave emit) ----
    {
        const int chunk = (M + 63) >> 6;     // contiguous slots per lane
        int lo = lane * chunk;
        int hi = lo + chunk; if (hi > M) hi = M;
        int cnt2 = 0;
        for (int jj = lo; jj < hi; ++jj) cnt2 += s_keep[jj];
        int inc2 = cnt2;
        for (int off = 1; off < 64; off <<= 1) {
            int n = __shfl_up(inc2, off, 64);
            if (lane >= off) inc2 += n;
        }
        int epos = inc2 - cnt2;              // exclusive prefix
        const int total = __shfl(inc2, 63, 64);

        float* osc = ws_scores + ((size_t)b * NMS_NUM_CLASSES + c) * NMS_MAX_PER_CLASS;
        float* obx = ws_boxes + (((size_t)b * NMS_NUM_CLASSES + c) * NMS_MAX_PER_CLASS) * 4;
        for (int jj = lo; jj < hi; ++jj) {
            if (s_keep[jj]) {
                if (epos < NMS_MAX_PER_CLASS) {
                    osc[epos] = s_sc[jj];
                    obx[epos * 4 + 0] = s_bx[jj * 4 + 0];
                    obx[epos * 4 + 1] = s_bx[jj * 4 + 1];
                    obx[epos * 4 + 2] = s_bx[jj * 4 + 2];
                    obx[epos * 4 + 3] = s_bx[jj * 4 + 3];
                }
                epos++;
            }
        }
        // pad positions [total, 100) with -1
        for (int pp = lane; pp < NMS_MAX_PER_CLASS; pp += 64) {
            if (pp >= total) osc[pp] = -1.0f;
        }
    }
}

// ---------------------------------------------------------------------------
// Kernel 2: one block per (image, class), 256 threads. Task-parallel partial
// ranks. BYTE-IDENTICAL to round-12 (passed, absmax 0).
// ---------------------------------------------------------------------------
__global__ __launch_bounds__(256) void nms_topk_kernel(
    const float* __restrict__ ws_scores,   // [B, 1600]
    const float* __restrict__ ws_boxes,    // [B, 1600, 4]
    float* __restrict__ out,               // [B*600] rows + [B] nvalid
    int B)
{
    const int b = blockIdx.x / NMS_NUM_CLASSES;
    const int c = blockIdx.x % NMS_NUM_CLASSES;
    const int cbase = c * NMS_MAX_PER_CLASS;
    __shared__ float s_sc[NMS_NS];
    __shared__ int s_rank[NMS_MAX_PER_CLASS];

    const float* isc = ws_scores + (size_t)b * NMS_NS;
    for (int t = threadIdx.x; t < NMS_NS; t += blockDim.x) s_sc[t] = isc[t];
    if (threadIdx.x < NMS_MAX_PER_CLASS) s_rank[threadIdx.x] = 0;
    __syncthreads();

    for (int task = threadIdx.x; task < NMS_MAX_PER_CLASS * 16; task += blockDim.x) {
        const int slot = task % NMS_MAX_PER_CLASS;
        const int chunk = task / NMS_MAX_PER_CLASS;
        const int flat = cbase + slot;
        const float s = s_sc[flat];
        const int j0 = chunk * 100;
        int rk = 0;
        for (int j = j0; j < j0 + 100; ++j) {
            float sj = s_sc[j];
            rk += (sj > s) || (sj == s && j < flat);
        }
        if (rk) atomicAdd(&s_rank[slot], rk);
    }
    __syncthreads();

    int is_top = 0;
    const int t = threadIdx.x;
    if (t < NMS_MAX_PER_CLASS) {
        const int slot = cbase + t;
        float s = s_sc[slot];
        if (s > NMS_SCORE_TH) {
            int rk = s_rank[t];
            if (rk < NMS_MAX_DET) {
                const float* bx = ws_boxes + ((size_t)b * NMS_NS + slot) * 4;
                float* row = out + (size_t)b * NMS_MAX_DET * 6 + rk * 6;
                row[0] = bx[0];
                row[1] = bx[1];
                row[2] = bx[2];
                row[3] = bx[3];
                row[4] = (float)c;
                row[5] = s;
                is_top = 1;
            }
        }
    }
    unsigned long long m = __ballot(is_top);
    if ((threadIdx.x & 63) == 0) {
        float cnt = (float)__popcll(m);
        if (cnt > 0.0f)
            atomicAdd(&out[(size_t)B * NMS_MAX_DET * 6 + b], cnt);
    }
}

extern "C" void kernel_launch(void* const* d_in, const int* in_sizes, int n_in,
                              void* d_out, int out_size, void* d_ws, size_t ws_size,
                              hipStream_t stream) {
    const float* pred = (const float*)d_in[0];
    const int B = in_sizes[0] / (NMS_N * 6);
    if (B <= 0) return;
    float* out = (float*)d_out;

    float* ws_scores = (float*)d_ws;
    float* ws_boxes = ws_scores + (size_t)B * NMS_NS;

    nms_per_class_kernel<<<dim3(B * NMS_NUM_CLASSES), dim3(64), 0, stream>>>(
        pred, ws_scores, ws_boxes, out, B);
    nms_topk_kernel<<<dim3(B * NMS_NUM_CLASSES), dim3(256), 0, stream>>>(
        ws_scores, ws_boxes, out, B);
}

// Round 3
// 123.976 us; speedup vs baseline: 1.3306x; 1.3306x over previous
//
#include <hip/hip_runtime.h>

#define NMS_NUM_CLASSES 16
#define NMS_N 2048
#define NMS_IOU_TH 0.5f
#define NMS_SCORE_TH 0.05f
#define NMS_MAX_DET 100
#define NMS_MAX_PER_CLASS 100
#define NMS_NS (NMS_NUM_CLASSES * NMS_MAX_PER_CLASS)   // 1600
#define NMS_TILE 128

// SESSION PITFALLS (r1-r22):
//  * float4 casts on __shared__ float -> ds_read_b128 misalignment fault.
//  * u64 LDS arrays / LDS pointer casts correlated with container deaths.
//    ONLY declared __shared__ float/uint/uchar arrays, scalar access.
//  * Serial NMS chains cost 45-65 us at M~122 -> Jacobi fixpoint (r15).
//  * Fusion via grid.sync REGRESSED (+5us): launch gaps ~1.4us in graphs.
//  * r20: removing ~6 of ~14 barriers with 1024 thr: NO change. Barrier
//    count is not the cost at 16 waves.
//  * r21: SINGLE-wave blocks: k1 39.8 -> 91.5 us. One wave = zero latency
//    hiding (occupancy 0.32%, VALUBusy 1.1%); every LDS chain exposed.
//  * Constant across r20/r21: total - k1 ~= 73.7 us (k2 + harness fixed).
//  * r22 (this round): 4 waves / 256 thr. O(M^2) phases (supc, rank)
//    split across 4 SIMDs; Jacobi + emit stay 1-wave register-resident
//    (r21-proven cheap). ~6 barriers at 4 waves each.

// ---------------------------------------------------------------------------
// Kernel 1: one block per (image, class), 256 threads (4 waves).
// ---------------------------------------------------------------------------
__global__ __launch_bounds__(256) void nms_per_class_kernel(
    const float* __restrict__ pred,   // [B, N, 6] x1,y1,x2,y2,cls,score
    float* __restrict__ ws_scores,    // [B, 1600]
    float* __restrict__ ws_boxes,     // [B, 1600, 4]
    float* __restrict__ out,          // [B*600] rows + [B] nvalid
    int B)
{
    const int b = blockIdx.x / NMS_NUM_CLASSES;
    const int c = blockIdx.x % NMS_NUM_CLASSES;
    const float* p = pred + (size_t)b * NMS_N * 6;
    const int tid = threadIdx.x;
    const int lane = tid & 63;
    const int w = tid >> 6;                  // wave id 0..3

    // zero-init output for this image (k2 is a later dispatch on the stream)
    if (c == 0) {
        float* ob = out + (size_t)b * NMS_MAX_DET * 6;
        for (int t = tid; t < NMS_MAX_DET * 6; t += 256) ob[t] = 0.0f;
        if (tid == 0) out[(size_t)B * NMS_MAX_DET * 6 + b] = 0.0f;
    }

    __shared__ float s_scu[NMS_N];           // unsorted scores
    __shared__ int   s_ixu[NMS_N];           // unsorted original indices
    __shared__ float s_bxu[NMS_N * 4];       // unsorted boxes
    __shared__ float s_sc[NMS_N];            // sorted scores
    __shared__ float s_bx[NMS_N * 4];        // sorted boxes
    __shared__ unsigned char s_keep[NMS_N];
    __shared__ unsigned int s_supc[4 * NMS_TILE];  // [window][col], stride-1
    __shared__ int s_m;

    if (tid == 0) s_m = 0;
    __syncthreads();

    // ---- compact: wave-aggregated (r20-proven), 8 trips over 2048 rows ----
    const float2* p2 = (const float2*)p;     // row i = p2[3i], p2[3i+1], p2[3i+2]
    for (int i = tid; i < NMS_N; i += 256) { // uniform trips
        float2 v0 = p2[i * 3 + 0];           // x1, y1
        float2 v1 = p2[i * 3 + 1];           // x2, y2
        float2 v2 = p2[i * 3 + 2];           // cls, score
        const bool ok = ((int)v2.x == c) && (v2.y > NMS_SCORE_TH);
        unsigned long long mask = __ballot(ok);
        int base = 0;
        if (lane == 0) {
            int cnt = __popcll(mask);
            if (cnt) base = atomicAdd(&s_m, cnt);
        }
        base = __shfl(base, 0, 64);
        if (ok) {
            int pos = base + __popcll(mask & ((1ull << lane) - 1ull));
            s_scu[pos] = v2.y;
            s_ixu[pos] = i;
            s_bxu[pos * 4 + 0] = v0.x;
            s_bxu[pos * 4 + 1] = v0.y;
            s_bxu[pos * 4 + 2] = v1.x;
            s_bxu[pos * 4 + 3] = v1.y;
        }
    }
    __syncthreads();
    const int M = s_m;

    // ---- rank sort + scatter: thread t owns column t (broadcast reads,
    //      no atomics, no s_rk; comparator identical to r12-proven) ----
    for (int q = tid; q < M; q += 256) {
        const float sq = s_scu[q];
        const int   iq = s_ixu[q];
        int rk = 0;
        for (int j = 0; j < M; ++j) {
            const float sj = s_scu[j];       // broadcast read
            const int   ij = s_ixu[j];       // broadcast read
            rk += (sj > sq) || (sj == sq && ij < iq);
        }
        s_sc[rk] = sq;
        s_bx[rk * 4 + 0] = s_bxu[q * 4 + 0];
        s_bx[rk * 4 + 1] = s_bxu[q * 4 + 1];
        s_bx[rk * 4 + 2] = s_bxu[q * 4 + 2];
        s_bx[rk * 4 + 3] = s_bxu[q * 4 + 3];
        s_keep[rk] = 1;
    }
    __syncthreads();

    // ---- tiled NMS ----
    for (int t0 = 0; t0 < M; t0 += NMS_TILE) {
        const int tm = (M - t0 < NMS_TILE) ? (M - t0) : NMS_TILE;

        // A0: suppression by kept candidates of earlier tiles (final state)
        if (t0 > 0) {
            for (int jj = tid; jj < tm; jj += 256) {
                const int gj = t0 + jj;
                float jx1 = s_bx[gj * 4 + 0], jy1 = s_bx[gj * 4 + 1];
                float jx2 = s_bx[gj * 4 + 2], jy2 = s_bx[gj * 4 + 3];
                float aj = (jy2 - jy1) * (jx2 - jx1);
                int dead = 0;
                for (int i = 0; i < t0 && !dead; ++i) {
                    if (!s_keep[i]) continue;
                    float ix1 = s_bx[i * 4 + 0], iy1 = s_bx[i * 4 + 1];
                    float ix2 = s_bx[i * 4 + 2], iy2 = s_bx[i * 4 + 3];
                    float ai = (iy2 - iy1) * (ix2 - ix1);
                    float ih = fminf(iy2, jy2) - fmaxf(iy1, jy1);
                    ih = fmaxf(ih, 0.0f);
                    float iw = fminf(ix2, jx2) - fmaxf(ix1, jx1);
                    iw = fmaxf(iw, 0.0f);
                    float inter = ih * iw;
                    float uni = ai + aj - inter;
                    float iou = (inter > 0.0f) ? inter / fmaxf(uni, 1e-08f) : 0.0f;
                    dead = iou > NMS_IOU_TH;
                }
                if (dead) s_keep[gj] = 0;
            }
            __syncthreads();
        }

        // supc: wave w computes window w (rows w*32..w*32+31) partial masks
        // for columns j0=lane, j1=lane+64. Register-accumulated, one LDS
        // store per (window,col) to s_supc[w*128+col] (stride-1, no conflict).
        {
            const int j0 = lane, j1 = lane + 64;
            const bool h0 = j0 < tm, h1 = j1 < tm;
            float a0x1 = 0, a0y1 = 0, a0x2 = 0, a0y2 = 0, ar0 = 0;
            float a1x1 = 0, a1y1 = 0, a1x2 = 0, a1y2 = 0, ar1 = 0;
            if (h0) {
                const int g = t0 + j0;
                a0x1 = s_bx[g * 4 + 0]; a0y1 = s_bx[g * 4 + 1];
                a0x2 = s_bx[g * 4 + 2]; a0y2 = s_bx[g * 4 + 3];
                ar0 = (a0y2 - a0y1) * (a0x2 - a0x1);
            }
            if (h1) {
                const int g = t0 + j1;
                a1x1 = s_bx[g * 4 + 0]; a1y1 = s_bx[g * 4 + 1];
                a1x2 = s_bx[g * 4 + 2]; a1y2 = s_bx[g * 4 + 3];
                ar1 = (a1y2 - a1y1) * (a1x2 - a1x1);
            }
            unsigned int mw0 = 0, mw1 = 0;
            const int i0 = w * 32;
            int iemax = tm - i0; if (iemax > 32) iemax = 32;
            for (int bb = 0; bb < iemax; ++bb) {
                const int ii = i0 + bb;
                const int gi = t0 + ii;
                float ix1 = s_bx[gi * 4 + 0], iy1 = s_bx[gi * 4 + 1];
                float ix2 = s_bx[gi * 4 + 2], iy2 = s_bx[gi * 4 + 3];
                float ai = (iy2 - iy1) * (ix2 - ix1);
                if (h0 && ii < j0) {
                    float ih = fminf(iy2, a0y2) - fmaxf(iy1, a0y1);
                    ih = fmaxf(ih, 0.0f);
                    float iw = fminf(ix2, a0x2) - fmaxf(ix1, a0x1);
                    iw = fmaxf(iw, 0.0f);
                    float inter = ih * iw;
                    float uni = ai + ar0 - inter;
                    float iou = (inter > 0.0f) ? inter / fmaxf(uni, 1e-08f) : 0.0f;
                    if (iou > NMS_IOU_TH) mw0 |= (1u << bb);
                }
                if (h1 && ii < j1) {
                    float ih = fminf(iy2, a1y2) - fmaxf(iy1, a1y1);
                    ih = fmaxf(ih, 0.0f);
                    float iw = fminf(ix2, a1x2) - fmaxf(ix1, a1x1);
                    iw = fmaxf(iw, 0.0f);
                    float inter = ih * iw;
                    float uni = ai + ar1 - inter;
                    float iou = (inter > 0.0f) ? inter / fmaxf(uni, 1e-08f) : 0.0f;
                    if (iou > NMS_IOU_TH) mw1 |= (1u << bb);
                }
            }
            if (h0) s_supc[w * NMS_TILE + j0] = mw0;
            if (h1) s_supc[w * NMS_TILE + j1] = mw1;
        }
        __syncthreads();                     // supc complete

        // Jacobi fixpoint: wave 0 only, register/ballot-resident (r21-proven)
        if (w == 0) {
            const int j0 = lane, j1 = lane + 64;
            const bool h0 = j0 < tm, h1 = j1 < tm;
            unsigned int m00 = 0, m01 = 0, m02 = 0, m03 = 0;
            unsigned int m10 = 0, m11 = 0, m12 = 0, m13 = 0;
            int ext0 = 0, ext1 = 0;
            if (h0) {
                m00 = s_supc[0 * NMS_TILE + j0];
                m01 = s_supc[1 * NMS_TILE + j0];
                m02 = s_supc[2 * NMS_TILE + j0];
                m03 = s_supc[3 * NMS_TILE + j0];
                ext0 = (int)s_keep[t0 + j0];
            }
            if (h1) {
                m10 = s_supc[0 * NMS_TILE + j1];
                m11 = s_supc[1 * NMS_TILE + j1];
                m12 = s_supc[2 * NMS_TILE + j1];
                m13 = s_supc[3 * NMS_TILE + j1];
                ext1 = (int)s_keep[t0 + j1];
            }
            int alive0 = ext0, alive1 = ext1;
            for (int round = 0; round < NMS_TILE; ++round) {
                unsigned long long A0b = __ballot(alive0 != 0);  // cols 0..63
                unsigned long long A1b = __ballot(alive1 != 0);  // cols 64..127
                const unsigned int kw0 = (unsigned int)(A0b & 0xffffffffu);
                const unsigned int kw1 = (unsigned int)(A0b >> 32);
                const unsigned int kw2 = (unsigned int)(A1b & 0xffffffffu);
                const unsigned int kw3 = (unsigned int)(A1b >> 32);
                int na0 = 0, na1 = 0;
                if (ext0)
                    na0 = (((m00 & kw0) | (m01 & kw1) | (m02 & kw2) | (m03 & kw3)) == 0u);
                if (ext1)
                    na1 = (((m10 & kw0) | (m11 & kw1) | (m12 & kw2) | (m13 & kw3)) == 0u);
                const unsigned long long chg =
                    __ballot(na0 != alive0) | __ballot(na1 != alive1);
                alive0 = na0; alive1 = na1;
                if (chg == 0ull) break;      // uniform within wave
            }
            if (h0) s_keep[t0 + j0] = (unsigned char)alive0;
            if (h1) s_keep[t0 + j1] = (unsigned char)alive1;
        }
        __syncthreads();                     // keep state final for this tile
    }

    // ---- emit top-100 kept in sorted order: wave 0 only (r21-proven) ----
    if (w == 0) {
        const int chunk = (M + 63) >> 6;     // contiguous slots per lane
        int lo = lane * chunk;
        int hi = lo + chunk; if (hi > M) hi = M;
        int cnt2 = 0;
        for (int jj = lo; jj < hi; ++jj) cnt2 += s_keep[jj];
        int inc2 = cnt2;
        for (int off = 1; off < 64; off <<= 1) {
            int n = __shfl_up(inc2, off, 64);
            if (lane >= off) inc2 += n;
        }
        int epos = inc2 - cnt2;              // exclusive prefix
        const int total = __shfl(inc2, 63, 64);

        float* osc = ws_scores + ((size_t)b * NMS_NUM_CLASSES + c) * NMS_MAX_PER_CLASS;
        float* obx = ws_boxes + (((size_t)b * NMS_NUM_CLASSES + c) * NMS_MAX_PER_CLASS) * 4;
        for (int jj = lo; jj < hi; ++jj) {
            if (s_keep[jj]) {
                if (epos < NMS_MAX_PER_CLASS) {
                    osc[epos] = s_sc[jj];
                    obx[epos * 4 + 0] = s_bx[jj * 4 + 0];
                    obx[epos * 4 + 1] = s_bx[jj * 4 + 1];
                    obx[epos * 4 + 2] = s_bx[jj * 4 + 2];
                    obx[epos * 4 + 3] = s_bx[jj * 4 + 3];
                }
                epos++;
            }
        }
        // pad positions [total, 100) with -1
        for (int pp = lane; pp < NMS_MAX_PER_CLASS; pp += 64) {
            if (pp >= total) osc[pp] = -1.0f;
        }
    }
}

// ---------------------------------------------------------------------------
// Kernel 2: one block per (image, class), 256 threads. Task-parallel partial
// ranks. BYTE-IDENTICAL to round-12 (passed, absmax 0).
// ---------------------------------------------------------------------------
__global__ __launch_bounds__(256) void nms_topk_kernel(
    const float* __restrict__ ws_scores,   // [B, 1600]
    const float* __restrict__ ws_boxes,    // [B, 1600, 4]
    float* __restrict__ out,               // [B*600] rows + [B] nvalid
    int B)
{
    const int b = blockIdx.x / NMS_NUM_CLASSES;
    const int c = blockIdx.x % NMS_NUM_CLASSES;
    const int cbase = c * NMS_MAX_PER_CLASS;
    __shared__ float s_sc[NMS_NS];
    __shared__ int s_rank[NMS_MAX_PER_CLASS];

    const float* isc = ws_scores + (size_t)b * NMS_NS;
    for (int t = threadIdx.x; t < NMS_NS; t += blockDim.x) s_sc[t] = isc[t];
    if (threadIdx.x < NMS_MAX_PER_CLASS) s_rank[threadIdx.x] = 0;
    __syncthreads();

    for (int task = threadIdx.x; task < NMS_MAX_PER_CLASS * 16; task += blockDim.x) {
        const int slot = task % NMS_MAX_PER_CLASS;
        const int chunk = task / NMS_MAX_PER_CLASS;
        const int flat = cbase + slot;
        const float s = s_sc[flat];
        const int j0 = chunk * 100;
        int rk = 0;
        for (int j = j0; j < j0 + 100; ++j) {
            float sj = s_sc[j];
            rk += (sj > s) || (sj == s && j < flat);
        }
        if (rk) atomicAdd(&s_rank[slot], rk);
    }
    __syncthreads();

    int is_top = 0;
    const int t = threadIdx.x;
    if (t < NMS_MAX_PER_CLASS) {
        const int slot = cbase + t;
        float s = s_sc[slot];
        if (s > NMS_SCORE_TH) {
            int rk = s_rank[t];
            if (rk < NMS_MAX_DET) {
                const float* bx = ws_boxes + ((size_t)b * NMS_NS + slot) * 4;
                float* row = out + (size_t)b * NMS_MAX_DET * 6 + rk * 6;
                row[0] = bx[0];
                row[1] = bx[1];
                row[2] = bx[2];
                row[3] = bx[3];
                row[4] = (float)c;
                row[5] = s;
                is_top = 1;
            }
        }
    }
    unsigned long long m = __ballot(is_top);
    if ((threadIdx.x & 63) == 0) {
        float cnt = (float)__popcll(m);
        if (cnt > 0.0f)
            atomicAdd(&out[(size_t)B * NMS_MAX_DET * 6 + b], cnt);
    }
}

extern "C" void kernel_launch(void* const* d_in, const int* in_sizes, int n_in,
                              void* d_out, int out_size, void* d_ws, size_t ws_size,
                              hipStream_t stream) {
    const float* pred = (const float*)d_in[0];
    const int B = in_sizes[0] / (NMS_N * 6);
    if (B <= 0) return;
    float* out = (float*)d_out;

    float* ws_scores = (float*)d_ws;
    float* ws_boxes = ws_scores + (size_t)B * NMS_NS;

    nms_per_class_kernel<<<dim3(B * NMS_NUM_CLASSES), dim3(256), 0, stream>>>(
        pred, ws_scores, ws_boxes, out, B);
    nms_topk_kernel<<<dim3(B * NMS_NUM_CLASSES), dim3(256), 0, stream>>>(
        ws_scores, ws_boxes, out, B);
}

// Round 4
// 93.947 us; speedup vs baseline: 1.7559x; 1.3196x over previous
//
#include <hip/hip_runtime.h>

#define NMS_NUM_CLASSES 16
#define NMS_N 2048
#define NMS_IOU_TH 0.5f
#define NMS_SCORE_TH 0.05f
#define NMS_MAX_DET 100
#define NMS_MAX_PER_CLASS 100
#define NMS_NS (NMS_NUM_CLASSES * NMS_MAX_PER_CLASS)   // 1600
#define NMS_TILE 128

// SESSION PITFALLS (r1-r23):
//  * float4 casts on __shared__ float -> ds_read_b128 misalignment fault.
//  * u64 LDS arrays / LDS pointer casts correlated with container deaths.
//    ONLY declared __shared__ float/uint/uchar arrays, scalar access.
//  * Serial NMS chains cost 45-65 us at M~122 -> Jacobi fixpoint (r15).
//  * Fusion via grid.sync REGRESSED (+5us): launch gaps ~1.4us in graphs.
//  * r20: removing ~6 of ~14 barriers at 16 waves: NO change. Not barriers.
//  * r21/r22: wave-count law T(k1) = 36.5us + 55us/waves (r21 1w=91.5,
//    r22 4w=50.2, r20 16w=39.8). Parallel term saturates at 16 waves;
//    36.5us serial = per-thread LDS chains inside phases (rank j-loop,
//    supc window loop) that don't shrink with waves.
//  * r23 (this round): 1024 thr (16 waves) + manual 4x-unrolled BRANCHLESS
//    inner loops (bitwise comparators, no ||; independent accumulators) to
//    batch ds_reads; Jacobi+emit stay r22 wave0 register versions. k2 gets
//    1024 thr + same unroll (est. 20-30us, never touched before).

__device__ __forceinline__ int nms_cmp(float sj, int ij, float sq, int iq) {
    // EXACT r12 comparator semantics, bitwise (no short-circuit branches)
    return ((int)(sj > sq)) | (((int)(sj == sq)) & ((int)(ij < iq)));
}

// ---------------------------------------------------------------------------
// Kernel 1: one block per (image, class), 1024 threads (16 waves).
// ---------------------------------------------------------------------------
__global__ __launch_bounds__(1024) void nms_per_class_kernel(
    const float* __restrict__ pred,   // [B, N, 6] x1,y1,x2,y2,cls,score
    float* __restrict__ ws_scores,    // [B, 1600]
    float* __restrict__ ws_boxes,     // [B, 1600, 4]
    float* __restrict__ out,          // [B*600] rows + [B] nvalid
    int B)
{
    const int b = blockIdx.x / NMS_NUM_CLASSES;
    const int c = blockIdx.x % NMS_NUM_CLASSES;
    const float* p = pred + (size_t)b * NMS_N * 6;
    const int tid = threadIdx.x;
    const int lane = tid & 63;
    const int w = tid >> 6;                  // wave id 0..15

    // zero-init output for this image (k2 is a later dispatch on the stream)
    if (c == 0) {
        float* ob = out + (size_t)b * NMS_MAX_DET * 6;
        for (int t = tid; t < NMS_MAX_DET * 6; t += 1024) ob[t] = 0.0f;
        if (tid == 0) out[(size_t)B * NMS_MAX_DET * 6 + b] = 0.0f;
    }

    __shared__ float s_scu[NMS_N];           // unsorted scores
    __shared__ int   s_ixu[NMS_N];           // unsorted original indices
    __shared__ float s_bxu[NMS_N * 4];       // unsorted boxes
    __shared__ int   s_rk[NMS_N];            // rank accumulators
    __shared__ float s_sc[NMS_N];            // sorted scores
    __shared__ float s_bx[NMS_N * 4];        // sorted boxes
    __shared__ unsigned char s_keep[NMS_N];
    __shared__ unsigned int s_supc[4 * NMS_TILE];  // [window][col], stride-1
    __shared__ int s_m;

    if (tid == 0) s_m = 0;
    __syncthreads();

    // ---- compact: wave-aggregated (r20-proven), 2 trips; s_rk zero fused ----
    const float2* p2 = (const float2*)p;     // row i = p2[3i], p2[3i+1], p2[3i+2]
    for (int i = tid; i < NMS_N; i += 1024) { // uniform trips
        s_rk[i] = 0;
        float2 v0 = p2[i * 3 + 0];           // x1, y1
        float2 v1 = p2[i * 3 + 1];           // x2, y2
        float2 v2 = p2[i * 3 + 2];           // cls, score
        const bool ok = ((int)v2.x == c) && (v2.y > NMS_SCORE_TH);
        unsigned long long mask = __ballot(ok);
        int base = 0;
        if (lane == 0) {
            int cnt = __popcll(mask);
            if (cnt) base = atomicAdd(&s_m, cnt);
        }
        base = __shfl(base, 0, 64);
        if (ok) {
            int pos = base + __popcll(mask & ((1ull << lane) - 1ull));
            s_scu[pos] = v2.y;
            s_ixu[pos] = i;
            s_bxu[pos * 4 + 0] = v0.x;
            s_bxu[pos * 4 + 1] = v0.y;
            s_bxu[pos * 4 + 2] = v1.x;
            s_bxu[pos * 4 + 3] = v1.y;
        }
    }
    __syncthreads();
    const int M = s_m;

    // ---- rank: (q, 32-chunk) tasks, branchless 4x-unrolled inner loop ----
    {
        const int nch = (M + 31) >> 5;
        const int ntask = M * nch;
        for (int task = tid; task < ntask; task += 1024) {
            const int q = task % M;          // consecutive tids -> distinct q
            const int ch = task / M;
            const float sq = s_scu[q];
            const int   iq = s_ixu[q];
            const int j0 = ch << 5;
            int jend = j0 + 32; if (jend > M) jend = M;
            int r0 = 0, r1 = 0, r2 = 0, r3 = 0;
            int j = j0;
            for (; j + 4 <= jend; j += 4) {
                float sa = s_scu[j + 0], sb = s_scu[j + 1];
                float sc2 = s_scu[j + 2], sd = s_scu[j + 3];
                int ia = s_ixu[j + 0], ib = s_ixu[j + 1];
                int ic = s_ixu[j + 2], id = s_ixu[j + 3];
                r0 += nms_cmp(sa, ia, sq, iq);
                r1 += nms_cmp(sb, ib, sq, iq);
                r2 += nms_cmp(sc2, ic, sq, iq);
                r3 += nms_cmp(sd, id, sq, iq);
            }
            for (; j < jend; ++j)
                r0 += nms_cmp(s_scu[j], s_ixu[j], sq, iq);
            const int rk = (r0 + r1) + (r2 + r3);
            if (rk) atomicAdd(&s_rk[q], rk);
        }
    }
    __syncthreads();
    for (int q = tid; q < M; q += 1024) {
        int rk = s_rk[q];
        s_sc[rk] = s_scu[q];
        s_bx[rk * 4 + 0] = s_bxu[q * 4 + 0];
        s_bx[rk * 4 + 1] = s_bxu[q * 4 + 1];
        s_bx[rk * 4 + 2] = s_bxu[q * 4 + 2];
        s_bx[rk * 4 + 3] = s_bxu[q * 4 + 3];
        s_keep[rk] = 1;
    }
    __syncthreads();

    // ---- tiled NMS ----
    for (int t0 = 0; t0 < M; t0 += NMS_TILE) {
        const int tm = (M - t0 < NMS_TILE) ? (M - t0) : NMS_TILE;

        // A0: suppression by kept candidates of earlier tiles (final state)
        if (t0 > 0) {
            for (int jj = tid; jj < tm; jj += 1024) {
                const int gj = t0 + jj;
                float jx1 = s_bx[gj * 4 + 0], jy1 = s_bx[gj * 4 + 1];
                float jx2 = s_bx[gj * 4 + 2], jy2 = s_bx[gj * 4 + 3];
                float aj = (jy2 - jy1) * (jx2 - jx1);
                int dead = 0;
                for (int i = 0; i < t0 && !dead; ++i) {
                    if (!s_keep[i]) continue;
                    float ix1 = s_bx[i * 4 + 0], iy1 = s_bx[i * 4 + 1];
                    float ix2 = s_bx[i * 4 + 2], iy2 = s_bx[i * 4 + 3];
                    float ai = (iy2 - iy1) * (ix2 - ix1);
                    float ih = fminf(iy2, jy2) - fmaxf(iy1, jy1);
                    ih = fmaxf(ih, 0.0f);
                    float iw = fminf(ix2, jx2) - fmaxf(ix1, jx1);
                    iw = fmaxf(iw, 0.0f);
                    float inter = ih * iw;
                    float uni = ai + aj - inter;
                    float iou = (inter > 0.0f) ? inter / fmaxf(uni, 1e-08f) : 0.0f;
                    dead = iou > NMS_IOU_TH;
                }
                if (dead) s_keep[gj] = 0;
            }
            __syncthreads();
        }

        // supc: (wi, j) tasks, guard-free iend, branchless 4x-unrolled.
        for (int idx = tid; idx < 4 * tm; idx += 1024) {
            const int wi = idx / tm;
            const int jj = idx % tm;
            const int ibase = wi << 5;
            unsigned int m0 = 0, m1 = 0, m2 = 0, m3 = 0;
            int iend = jj - ibase;           // only i < j
            if (iend > 32) iend = 32;
            if (iend > 0) {
                const int gj = t0 + jj;
                float jx1 = s_bx[gj * 4 + 0], jy1 = s_bx[gj * 4 + 1];
                float jx2 = s_bx[gj * 4 + 2], jy2 = s_bx[gj * 4 + 3];
                float aj = (jy2 - jy1) * (jx2 - jx1);
                int bb = 0;
                for (; bb + 4 <= iend; bb += 4) {
#define NMS_SUP1(K, MK)                                                        \
                    {                                                          \
                        const int gi = t0 + ibase + bb + (K);                  \
                        float ix1 = s_bx[gi * 4 + 0], iy1 = s_bx[gi * 4 + 1];  \
                        float ix2 = s_bx[gi * 4 + 2], iy2 = s_bx[gi * 4 + 3];  \
                        float ai = (iy2 - iy1) * (ix2 - ix1);                  \
                        float ih = fminf(iy2, jy2) - fmaxf(iy1, jy1);          \
                        ih = fmaxf(ih, 0.0f);                                  \
                        float iw = fminf(ix2, jx2) - fmaxf(ix1, jx1);          \
                        iw = fmaxf(iw, 0.0f);                                  \
                        float inter = ih * iw;                                 \
                        float uni = ai + aj - inter;                           \
                        float iou = (inter > 0.0f) ? inter / fmaxf(uni, 1e-08f) : 0.0f; \
                        MK |= (iou > NMS_IOU_TH) ? (1u << (bb + (K))) : 0u;    \
                    }
                    NMS_SUP1(0, m0)
                    NMS_SUP1(1, m1)
                    NMS_SUP1(2, m2)
                    NMS_SUP1(3, m3)
                }
                for (; bb < iend; ++bb) {
                    const int gi = t0 + ibase + bb;
                    float ix1 = s_bx[gi * 4 + 0], iy1 = s_bx[gi * 4 + 1];
                    float ix2 = s_bx[gi * 4 + 2], iy2 = s_bx[gi * 4 + 3];
                    float ai = (iy2 - iy1) * (ix2 - ix1);
                    float ih = fminf(iy2, jy2) - fmaxf(iy1, jy1);
                    ih = fmaxf(ih, 0.0f);
                    float iw = fminf(ix2, jx2) - fmaxf(ix1, jx1);
                    iw = fmaxf(iw, 0.0f);
                    float inter = ih * iw;
                    float uni = ai + aj - inter;
                    float iou = (inter > 0.0f) ? inter / fmaxf(uni, 1e-08f) : 0.0f;
                    m0 |= (iou > NMS_IOU_TH) ? (1u << bb) : 0u;
                }
#undef NMS_SUP1
            }
            s_supc[wi * NMS_TILE + jj] = (m0 | m1) | (m2 | m3);
        }
        __syncthreads();                     // supc complete

        // Jacobi fixpoint: wave 0 only, register/ballot-resident (r22-proven)
        if (w == 0) {
            const int j0 = lane, j1 = lane + 64;
            const bool h0 = j0 < tm, h1 = j1 < tm;
            unsigned int m00 = 0, m01 = 0, m02 = 0, m03 = 0;
            unsigned int m10 = 0, m11 = 0, m12 = 0, m13 = 0;
            int ext0 = 0, ext1 = 0;
            if (h0) {
                m00 = s_supc[0 * NMS_TILE + j0];
                m01 = s_supc[1 * NMS_TILE + j0];
                m02 = s_supc[2 * NMS_TILE + j0];
                m03 = s_supc[3 * NMS_TILE + j0];
                ext0 = (int)s_keep[t0 + j0];
            }
            if (h1) {
                m10 = s_supc[0 * NMS_TILE + j1];
                m11 = s_supc[1 * NMS_TILE + j1];
                m12 = s_supc[2 * NMS_TILE + j1];
                m13 = s_supc[3 * NMS_TILE + j1];
                ext1 = (int)s_keep[t0 + j1];
            }
            int alive0 = ext0, alive1 = ext1;
            for (int round = 0; round < NMS_TILE; ++round) {
                unsigned long long A0b = __ballot(alive0 != 0);  // cols 0..63
                unsigned long long A1b = __ballot(alive1 != 0);  // cols 64..127
                const unsigned int kw0 = (unsigned int)(A0b & 0xffffffffu);
                const unsigned int kw1 = (unsigned int)(A0b >> 32);
                const unsigned int kw2 = (unsigned int)(A1b & 0xffffffffu);
                const unsigned int kw3 = (unsigned int)(A1b >> 32);
                int na0 = 0, na1 = 0;
                if (ext0)
                    na0 = (((m00 & kw0) | (m01 & kw1) | (m02 & kw2) | (m03 & kw3)) == 0u);
                if (ext1)
                    na1 = (((m10 & kw0) | (m11 & kw1) | (m12 & kw2) | (m13 & kw3)) == 0u);
                const unsigned long long chg =
                    __ballot(na0 != alive0) | __ballot(na1 != alive1);
                alive0 = na0; alive1 = na1;
                if (chg == 0ull) break;      // uniform within wave
            }
            if (h0) s_keep[t0 + j0] = (unsigned char)alive0;
            if (h1) s_keep[t0 + j1] = (unsigned char)alive1;
        }
        __syncthreads();                     // keep state final for this tile
    }

    // ---- emit top-100 kept in sorted order: wave 0 only (r21/r22-proven) ----
    if (w == 0) {
        const int chunk = (M + 63) >> 6;     // contiguous slots per lane
        int lo = lane * chunk;
        int hi = lo + chunk; if (hi > M) hi = M;
        int cnt2 = 0;
        for (int jj = lo; jj < hi; ++jj) cnt2 += s_keep[jj];
        int inc2 = cnt2;
        for (int off = 1; off < 64; off <<= 1) {
            int n = __shfl_up(inc2, off, 64);
            if (lane >= off) inc2 += n;
        }
        int epos = inc2 - cnt2;              // exclusive prefix
        const int total = __shfl(inc2, 63, 64);

        float* osc = ws_scores + ((size_t)b * NMS_NUM_CLASSES + c) * NMS_MAX_PER_CLASS;
        float* obx = ws_boxes + (((size_t)b * NMS_NUM_CLASSES + c) * NMS_MAX_PER_CLASS) * 4;
        for (int jj = lo; jj < hi; ++jj) {
            if (s_keep[jj]) {
                if (epos < NMS_MAX_PER_CLASS) {
                    osc[epos] = s_sc[jj];
                    obx[epos * 4 + 0] = s_bx[jj * 4 + 0];
                    obx[epos * 4 + 1] = s_bx[jj * 4 + 1];
                    obx[epos * 4 + 2] = s_bx[jj * 4 + 2];
                    obx[epos * 4 + 3] = s_bx[jj * 4 + 3];
                }
                epos++;
            }
        }
        // pad positions [total, 100) with -1
        for (int pp = lane; pp < NMS_MAX_PER_CLASS; pp += 64) {
            if (pp >= total) osc[pp] = -1.0f;
        }
    }
}

// ---------------------------------------------------------------------------
// Kernel 2: one block per (image, class), 1024 threads. Same rank algorithm
// as the r12-proven version (identical comparator + tie-break), with 4x the
// thread parallelism and a branchless 4x-unrolled inner loop.
// ---------------------------------------------------------------------------
__global__ __launch_bounds__(1024) void nms_topk_kernel(
    const float* __restrict__ ws_scores,   // [B, 1600]
    const float* __restrict__ ws_boxes,    // [B, 1600, 4]
    float* __restrict__ out,               // [B*600] rows + [B] nvalid
    int B)
{
    const int b = blockIdx.x / NMS_NUM_CLASSES;
    const int c = blockIdx.x % NMS_NUM_CLASSES;
    const int cbase = c * NMS_MAX_PER_CLASS;
    __shared__ float s_sc[NMS_NS];
    __shared__ int s_rank[NMS_MAX_PER_CLASS];

    const float* isc = ws_scores + (size_t)b * NMS_NS;
    for (int t = threadIdx.x; t < NMS_NS; t += blockDim.x) s_sc[t] = isc[t];
    if (threadIdx.x < NMS_MAX_PER_CLASS) s_rank[threadIdx.x] = 0;
    __syncthreads();

    for (int task = threadIdx.x; task < NMS_MAX_PER_CLASS * 16; task += blockDim.x) {
        const int slot = task % NMS_MAX_PER_CLASS;
        const int chunk = task / NMS_MAX_PER_CLASS;
        const int flat = cbase + slot;
        const float s = s_sc[flat];
        const int j0 = chunk * 100;
        int r0 = 0, r1 = 0, r2 = 0, r3 = 0;
        for (int j = j0; j < j0 + 100; j += 4) {
            float sa = s_sc[j + 0], sb = s_sc[j + 1];
            float sc2 = s_sc[j + 2], sd = s_sc[j + 3];
            r0 += ((int)(sa > s)) | (((int)(sa == s)) & ((int)(j + 0 < flat)));
            r1 += ((int)(sb > s)) | (((int)(sb == s)) & ((int)(j + 1 < flat)));
            r2 += ((int)(sc2 > s)) | (((int)(sc2 == s)) & ((int)(j + 2 < flat)));
            r3 += ((int)(sd > s)) | (((int)(sd == s)) & ((int)(j + 3 < flat)));
        }
        const int rk = (r0 + r1) + (r2 + r3);
        if (rk) atomicAdd(&s_rank[slot], rk);
    }
    __syncthreads();

    int is_top = 0;
    const int t = threadIdx.x;
    if (t < NMS_MAX_PER_CLASS) {
        const int slot = cbase + t;
        float s = s_sc[slot];
        if (s > NMS_SCORE_TH) {
            int rk = s_rank[t];
            if (rk < NMS_MAX_DET) {
                const float* bx = ws_boxes + ((size_t)b * NMS_NS + slot) * 4;
                float* row = out + (size_t)b * NMS_MAX_DET * 6 + rk * 6;
                row[0] = bx[0];
                row[1] = bx[1];
                row[2] = bx[2];
                row[3] = bx[3];
                row[4] = (float)c;
                row[5] = s;
                is_top = 1;
            }
        }
    }
    unsigned long long m = __ballot(is_top);
    if ((threadIdx.x & 63) == 0) {
        float cnt = (float)__popcll(m);
        if (cnt > 0.0f)
            atomicAdd(&out[(size_t)B * NMS_MAX_DET * 6 + b], cnt);
    }
}

extern "C" void kernel_launch(void* const* d_in, const int* in_sizes, int n_in,
                              void* d_out, int out_size, void* d_ws, size_t ws_size,
                              hipStream_t stream) {
    const float* pred = (const float*)d_in[0];
    const int B = in_sizes[0] / (NMS_N * 6);
    if (B <= 0) return;
    float* out = (float*)d_out;

    float* ws_scores = (float*)d_ws;
    float* ws_boxes = ws_scores + (size_t)B * NMS_NS;

    nms_per_class_kernel<<<dim3(B * NMS_NUM_CLASSES), dim3(1024), 0, stream>>>(
        pred, ws_scores, ws_boxes, out, B);
    nms_topk_kernel<<<dim3(B * NMS_NUM_CLASSES), dim3(1024), 0, stream>>>(
        ws_scores, ws_boxes, out, B);
}